// Round 2
// baseline (90.084 us; speedup 1.0000x reference)
//
#include <hip/hip_runtime.h>
#include <math.h>

#define IMG_H 512
#define IMG_W 512
#define NB 9

// One thread per pooled 8x8 cell.
//
// CORRECTNESS MODEL: the harness's "np" reference is a dtype-faithful float32
// port of the jax graph. The bin decision (floor/ceil of phase_bin) is a hard
// discontinuity, so we must reproduce the float32 chain bit-exactly:
//   gray  = ((c0+c1)+c2)/3           fp32, numpy mean order, IEEE division
//   gx,gy = Sobel taps               all weights +-1/+-2 -> multiplies exact;
//                                    additions in tap-lexicographic order
//   phase = (float)atan2(fp64)       == correctly-rounded fp32 atan2
//                                    (matches numpy's f32 arctan2)
//   pb    = phase / (float)pi * 9    two fp32 roundings, same as numpy
// norm and pooled accumulation are value-continuous -> plain fp32 is fine.
__global__ __launch_bounds__(256) void hog_kernel(const float* __restrict__ x,
                                                  float* __restrict__ out) {
    const int tid = blockIdx.x * 256 + threadIdx.x;   // 0 .. 131071
    const int n    = tid >> 12;        // image index (4096 cells/image)
    const int cell = tid & 4095;
    const int cy   = cell >> 6;
    const int cx   = cell & 63;
    const int h0   = cy * 8;
    const int w0   = cx * 8;
    const float* xn = x + (size_t)n * 3 * IMG_H * IMG_W;

    float bins[NB];
#pragma unroll
    for (int b = 0; b < NB; b++) bins[b] = 0.0f;

    // rolling 3 rows of 10 gray values (fp32)
    float rowbuf[3][10];

#define LOAD_ROW(HROW, SLOT)                                                     \
    {                                                                            \
        const int hh_ = (HROW);                                                  \
        if (hh_ < 0 || hh_ >= IMG_H) {                                           \
            _Pragma("unroll") for (int i_ = 0; i_ < 10; i_++) rowbuf[SLOT][i_] = 0.0f; \
        } else {                                                                 \
            const float* p_ = xn + (size_t)hh_ * IMG_W;                          \
            _Pragma("unroll") for (int i_ = 0; i_ < 10; i_++) {                  \
                const int ww_ = w0 - 1 + i_;                                     \
                if (ww_ < 0 || ww_ >= IMG_W) {                                   \
                    rowbuf[SLOT][i_] = 0.0f;                                     \
                } else {                                                         \
                    float a_ = p_[ww_];                                          \
                    float b_ = p_[IMG_H * IMG_W + ww_];                          \
                    float c_ = p_[2 * IMG_H * IMG_W + ww_];                      \
                    rowbuf[SLOT][i_] = ((a_ + b_) + c_) / 3.0f;                  \
                }                                                                \
            }                                                                    \
        }                                                                        \
    }

    LOAD_ROW(h0 - 1, 0)   // top row (may be padding)
    LOAD_ROW(h0,     1)   // mid row

#pragma unroll
    for (int hy = 0; hy < 8; hy++) {
        const int s_b = (hy + 2) % 3;   // bottom row h0+hy+1 goes here
        LOAD_ROW(h0 + hy + 1, s_b)
        const int s_t = hy % 3;         // row h0+hy-1
        const int s_m = (hy + 1) % 3;   // row h0+hy

#pragma unroll
        for (int j = 0; j < 8; j++) {
            const float tl = rowbuf[s_t][j], tc = rowbuf[s_t][j + 1], tr = rowbuf[s_t][j + 2];
            const float ml = rowbuf[s_m][j],                          mr = rowbuf[s_m][j + 2];
            const float bl = rowbuf[s_b][j], bc = rowbuf[s_b][j + 1], br = rowbuf[s_b][j + 2];

            // cross-correlation, tap-lexicographic addition order, exact mults
            const float gx = ((((tl - tr) + 2.0f * ml) - 2.0f * mr) + bl) - br;
            const float gy = ((((tl + 2.0f * tc) + tr) - bl) - 2.0f * bc) - br;

            const float nrm = sqrtf(gx * gx + gy * gy);

            // correctly-rounded fp32 atan2 via fp64, matching numpy f32 arctan2
            const float ph  = (float)atan2((double)gx, (double)gy);
            const float pbf = ph / (float)M_PI * 9.0f;   // two fp32 roundings

            int lo = (int)floorf(pbf) % NB; if (lo < 0) lo += NB;   // floored mod
            int hi = (int)ceilf(pbf)  % NB; if (hi < 0) hi += NB;

            const float om = 1.0f - nrm;
#pragma unroll
            for (int b = 0; b < NB; b++) {
                float add = 0.0f;
                if (b == lo) add += nrm;
                if (b == hi) add += om;
                bins[b] += add;
            }
        }
    }
#undef LOAD_ROW

    // out[n][b][cy][cx], pooled mean = sum / 64 (exact scaling)
    const size_t base = (size_t)n * NB * 4096 + (size_t)cy * 64 + cx;
#pragma unroll
    for (int b = 0; b < NB; b++)
        out[base + (size_t)b * 4096] = bins[b] * (1.0f / 64.0f);
}

extern "C" void kernel_launch(void* const* d_in, const int* in_sizes, int n_in,
                              void* d_out, int out_size, void* d_ws, size_t ws_size,
                              hipStream_t stream) {
    const float* x = (const float*)d_in[0];
    float* out = (float*)d_out;
    // 32 images * 64 * 64 cells = 131072 threads = 512 blocks of 256
    hog_kernel<<<512, 256, 0, stream>>>(x, out);
}